// Round 1
// baseline (537.730 us; speedup 1.0000x reference)
//
#include <hip/hip_runtime.h>
#include <math.h>

// Problem constants
constexpr int B = 256;
constexpr int C = 512;
constexpr int N = 512;
constexpr int K = 256;   // = B

// ws layout (floats)
constexpr size_t OFF_CLIPNB = 0;                            // B*C bf16 = B*C/2 floats
constexpr size_t OFF_INV    = OFF_CLIPNB + (size_t)B*C/2;   // B*N
constexpr size_t OFF_U4     = OFF_INV    + (size_t)B*N;     // 1024 slots * C
constexpr size_t OFF_PM     = OFF_U4     + (size_t)1024*C;  // 1024 slots * K
constexpr size_t OFF_PS     = OFF_PM     + (size_t)1024*K;
constexpr size_t OFF_PH     = OFF_PS     + (size_t)1024*K;
constexpr size_t OFF_PG     = OFF_PH     + (size_t)1024*K;
constexpr size_t OFF_SGLOB  = OFF_PG     + (size_t)1024*K;  // B*K
constexpr size_t OFF_SSOFT  = OFF_SGLOB  + (size_t)B*K;
constexpr size_t OFF_SHARD  = OFF_SSOFT  + (size_t)B*K;
constexpr size_t OFF_MISC   = OFF_SHARD  + (size_t)B*K;     // 7

typedef __attribute__((ext_vector_type(8))) short short8;
typedef __attribute__((ext_vector_type(4))) float f32x4;

__device__ __forceinline__ float wave_reduce_sum(float v) {
  #pragma unroll
  for (int off = 32; off > 0; off >>= 1) v += __shfl_xor(v, off, 64);
  return v;
}
__device__ __forceinline__ float wave_reduce_max(float v) {
  #pragma unroll
  for (int off = 32; off > 0; off >>= 1) v = fmaxf(v, __shfl_xor(v, off, 64));
  return v;
}
__device__ __forceinline__ unsigned int bf16_rne(float x) {
  unsigned int u = __builtin_bit_cast(unsigned int, x);
  return (u + 0x7FFFu + ((u >> 16) & 1u)) >> 16;
}
__device__ __forceinline__ unsigned int pk_bf16(float x, float y) {
  return bf16_rne(x) | (bf16_rne(y) << 16);
}

// ---------------- K0: scale + zero focal accumulators ----------------
__global__ void k_misc(const float* __restrict__ ls, float* __restrict__ misc) {
  int t = threadIdx.x;
  if (t == 0) misc[0] = fminf(fmaxf(expf(ls[0]), 0.01f), 100.0f);
  if (t >= 1 && t < 7) misc[t] = 0.0f;
}

// ---------------- K1: l2-normalize clip rows -> bf16 ----------------
__global__ __launch_bounds__(256) void k_rownorm(const float* __restrict__ src,
                                                 unsigned short* __restrict__ dst_bf) {
  int b = blockIdx.x, t = threadIdx.x;
  float x0 = src[(size_t)b * C + t];
  float x1 = src[(size_t)b * C + t + 256];
  __shared__ float red[4];
  float w = wave_reduce_sum(x0 * x0 + x1 * x1);
  if ((t & 63) == 0) red[t >> 6] = w;
  __syncthreads();
  float tot = red[0] + red[1] + red[2] + red[3];
  float r = 1.0f / fmaxf(sqrtf(tot), 1e-12f);
  dst_bf[(size_t)b * C + t] = (unsigned short)bf16_rne(x0 * r);
  dst_bf[(size_t)b * C + t + 256] = (unsigned short)bf16_rne(x1 * r);
}

// ---------------- K2: inv prepass: inv[b][n] = rsqrt(sum_c x^2) ----------------
// grid 512 = (b, half); 512 threads: slice=t>>6 owns 64 c's, lane owns 4 n's.
// Pure streaming, 16 waves/CU, fully coalesced (1KB per wave per c-row).
__global__ __launch_bounds__(512) void k_inv(const float* __restrict__ yolo,
                                             float* __restrict__ invg) {
  int bh = blockIdx.x;
  int b = bh >> 1, half = bh & 1;
  int t = threadIdx.x;
  int slice = t >> 6, lane = t & 63;
  const float* base = yolo + (size_t)b * C * N + half * 256 + 4 * lane;
  float4 ss = {0.f, 0.f, 0.f, 0.f};
  #pragma unroll 8
  for (int ci = 0; ci < 64; ci++) {
    float4 v = *(const float4*)(base + (size_t)(slice * 64 + ci) * N);
    ss.x += v.x * v.x; ss.y += v.y * v.y;
    ss.z += v.z * v.z; ss.w += v.w * v.w;
  }
  __shared__ float part[8][256];
  *(float4*)&part[slice][4 * lane] = ss;
  __syncthreads();
  if (t < 256) {
    float s = 0.f;
    #pragma unroll
    for (int g = 0; g < 8; g++) s += part[g][t];
    invg[(size_t)b * N + half * 256 + t] = 1.0f / fmaxf(sqrtf(s), 1e-12f);
  }
}

// ---------------- K3: fused main GEMM (bf16 MFMA), pipelined ----------------
// grid 512: block bh -> b = bh>>1, half = bh&1.
// Changes vs prior version:
//  - inv known upfront (k_inv): x-hat = x*inv folded at stage time -> epilogue
//    needs no inv, and u[c] = sum_n x-hat (for gnorm) falls out of staging
//    (dot(x4,iv4) + 5-step nf-butterfly) -> k_gnorm's 256MB pass DELETED.
//  - xl double-buffered (2x16KB); raw s_barrier + lgkmcnt(0)-only drain;
//    yolo loads for chunk cc+1 and A-frags issued BEFORE the barrier so HBM/L2
//    loads stay in flight across barrier + MFMA phase (no vmcnt(0) drain ever).
//  - per-window epilogue writes (m,s,h,g) partials to PM2/PS2/PH2/PG2
//    (4 slots per (b,k), merged in k_post) -> no persistent 48-VGPR state.
__global__ __launch_bounds__(256, 2) void k_main_mfma(
    const float* __restrict__ yolo,
    const unsigned short* __restrict__ clipnb,
    const float* __restrict__ invg,
    const float* __restrict__ misc,
    float* __restrict__ U4,
    float* __restrict__ PM2, float* __restrict__ PS2,
    float* __restrict__ PH2, float* __restrict__ PG2) {
  int bh = blockIdx.x;
  int b = bh >> 1, half = bh & 1;
  int t = threadIdx.x;
  int w = t >> 6, lane = t & 63;
  int quad = lane >> 4, col = lane & 15;

  __shared__ unsigned int xl[2][128 * 32];   // 2 x 16 KB, rotated rows

  const float scale = misc[0];
  const float* ybase = yolo + (size_t)b * C * N;

  int nf = t & 31;                 // 4-n group (n = 4nf+j)
  int cp0 = t >> 5;                // 0..7 (c-pair subset)
  unsigned int rotv = (8u * (nf & 3) + 4u * (unsigned)(nf >> 2)) & 31u;

  #pragma unroll 1
  for (int iter = 0; iter < 2; iter++) {
    int n0 = half * 256 + iter * 128;
    float4 iv4 = *(const float4*)(invg + (size_t)b * N + n0 + 4 * nf);

    f32x4 acc[4][8];
    #pragma unroll
    for (int kt = 0; kt < 4; kt++)
      #pragma unroll
      for (int nt = 0; nt < 8; nt++) {
        f32x4 z = {0.f, 0.f, 0.f, 0.f};
        acc[kt][nt] = z;
      }

    // prologue: issue chunk-0 yolo loads
    float4 Ya[4], Yb[4];
    #pragma unroll
    for (int p = 0; p < 4; p++) {
      const float* pa = ybase + (size_t)(2 * (cp0 + 8 * p)) * N + n0 + 4 * nf;
      Ya[p] = *(const float4*)pa;
      Yb[p] = *(const float4*)(pa + N);
    }

    #pragma unroll
    for (int cc = 0; cc < 8; cc++) {
      unsigned int* xbuf = &xl[cc & 1][0];
      int c0 = cc * 64;

      // ---- pack chunk cc: fold inv, bf16, transpose-write; u partials ----
      float up[8];
      #pragma unroll
      for (int p = 0; p < 4; p++) {
        float ax = Ya[p].x * iv4.x, ay = Ya[p].y * iv4.y,
              az = Ya[p].z * iv4.z, aw = Ya[p].w * iv4.w;
        float bx = Yb[p].x * iv4.x, by = Yb[p].y * iv4.y,
              bz = Yb[p].z * iv4.z, bw = Yb[p].w * iv4.w;
        unsigned int pos = ((unsigned)(cp0 + 8 * p) + rotv) & 31u;
        int base0 = (4 * nf) * 32;
        xbuf[base0 + pos]       = pk_bf16(ax, bx);
        xbuf[base0 + 32 + pos]  = pk_bf16(ay, by);
        xbuf[base0 + 64 + pos]  = pk_bf16(az, bz);
        xbuf[base0 + 96 + pos]  = pk_bf16(aw, bw);
        up[2 * p]     = ax + ay + az + aw;
        up[2 * p + 1] = bx + by + bz + bw;
      }

      // ---- issue NEXT chunk yolo loads (HBM) before the barrier ----
      if (cc < 7) {
        #pragma unroll
        for (int p = 0; p < 4; p++) {
          const float* pa =
              ybase + (size_t)((cc + 1) * 64 + 2 * (cp0 + 8 * p)) * N + n0 + 4 * nf;
          Ya[p] = *(const float4*)pa;
          Yb[p] = *(const float4*)(pa + N);
        }
      }
      // ---- A-frags for THIS chunk (L2-hot), also pre-barrier ----
      short8 afr[4][2];
      #pragma unroll
      for (int kt = 0; kt < 4; kt++)
        #pragma unroll
        for (int s = 0; s < 2; s++) {
          const unsigned short* ap =
              clipnb + (size_t)(64 * w + 16 * kt + col) * C + c0 + 32 * s + 8 * quad;
          union { uint4 u; short8 v; } fa;
          fa.u = *(const uint4*)ap;
          afr[kt][s] = fa.v;
        }

      // ---- u partial reduce over nf (window-n slice) + write U4 ----
      #pragma unroll
      for (int i = 0; i < 8; i++)
        #pragma unroll
        for (int o = 1; o < 32; o <<= 1)
          up[i] += __shfl_xor(up[i], o, 64);
      if (nf == 0) {
        size_t ub = ((size_t)bh * 2 + iter) * C;
        #pragma unroll
        for (int p = 0; p < 4; p++) {
          int c = c0 + 2 * (cp0 + 8 * p);
          *(float2*)&U4[ub + c] = make_float2(up[2 * p], up[2 * p + 1]);
        }
      }

      // ---- barrier: drain LDS writes only; global loads stay in flight ----
      asm volatile("s_waitcnt lgkmcnt(0)" ::: "memory");
      __builtin_amdgcn_s_barrier();

      // ---- MFMA phase: b128 frag reads, conflict-free bank tiling ----
      #pragma unroll
      for (int s = 0; s < 2; s++) {
        #pragma unroll
        for (int nt = 0; nt < 8; nt++) {
          int n = 16 * nt + col;
          unsigned int pos =
              (unsigned)(16 * s + 4 * quad + 8 * (col >> 2) + 4 * nt) & 31u;
          union { uint4 u; short8 v; } fb;
          fb.u = *(const uint4*)&xbuf[n * 32 + pos];
          #pragma unroll
          for (int kt = 0; kt < 4; kt++)
            acc[kt][nt] = __builtin_amdgcn_mfma_f32_16x16x32_bf16(
                afr[kt][s], fb.v, acc[kt][nt], 0, 0, 0);
        }
      }
    }

    // ---- per-window epilogue: online (m,s,h) + gsum, col-reduce, write ----
    size_t slot = (size_t)bh * 2 + iter;
    #pragma unroll
    for (int kt = 0; kt < 4; kt++)
      #pragma unroll
      for (int r = 0; r < 4; r++) {
        float mm = -1e30f, ss = 0.f, hh = -1e30f, gg = 0.f;
        #pragma unroll
        for (int nt = 0; nt < 8; nt++) {
          float vu = acc[kt][nt][r];        // already inv-normalized
          gg += vu;
          float v = vu * scale;
          hh = fmaxf(hh, v);
          float M = fmaxf(mm, v);
          ss = ss * __expf(mm - M) + __expf(v - M);
          mm = M;
        }
        #pragma unroll
        for (int o = 1; o < 16; o <<= 1) {
          float mo = __shfl_xor(mm, o, 64);
          float so = __shfl_xor(ss, o, 64);
          float ho = __shfl_xor(hh, o, 64);
          float go = __shfl_xor(gg, o, 64);
          float M = fmaxf(mm, mo);
          ss = ss * __expf(mm - M) + so * __expf(mo - M);
          mm = M;
          hh = fmaxf(hh, ho);
          gg += go;
        }
        if (col == 0) {
          int k = 64 * w + 16 * kt + 4 * quad + r;
          size_t a = slot * 256 + k;
          PM2[a] = mm; PS2[a] = ss; PH2[a] = hh; PG2[a] = gg;
        }
      }
  }
}

// ---------------- K4: merge partials: gn, Sglob, Ssoft, Shard ----------------
// block = b; slots 4b..4b+3 hold (half,iter) partials.
__global__ __launch_bounds__(256) void k_post(
    const float* __restrict__ U4, const float* __restrict__ PG2,
    const float* __restrict__ PM2, const float* __restrict__ PS2,
    const float* __restrict__ PH2, const float* __restrict__ misc,
    float* __restrict__ Sglob, float* __restrict__ Ssoft,
    float* __restrict__ Shard) {
  int bI = blockIdx.x;
  int t = threadIdx.x;
  __shared__ float red[4];
  __shared__ float gnS;
  // gn[b] = max(||u||/N, eps), u[c] = sum of 4 slot partials
  float sq = 0.f;
  #pragma unroll
  for (int cq = 0; cq < 2; cq++) {
    size_t u0 = ((size_t)bI * 4) * C + t + 256 * cq;
    float tot = U4[u0] + U4[u0 + C] + U4[u0 + 2 * C] + U4[u0 + 3 * C];
    sq += tot * tot;
  }
  float wsum = wave_reduce_sum(sq);
  if ((t & 63) == 0) red[t >> 6] = wsum;
  __syncthreads();
  if (t == 0) {
    float s = red[0] + red[1] + red[2] + red[3];
    gnS = fmaxf(sqrtf(s) * (1.0f / (float)N), 1e-12f);
  }
  __syncthreads();
  float gn = gnS;
  int k = t;
  size_t p0 = (size_t)bI * 4 * 256 + k;
  float g = PG2[p0] + PG2[p0 + 256] + PG2[p0 + 512] + PG2[p0 + 768];
  Sglob[(size_t)bI * K + k] = misc[0] * g * (1.0f / (float)N) / gn;
  float m0 = PM2[p0], m1 = PM2[p0 + 256], m2 = PM2[p0 + 512], m3 = PM2[p0 + 768];
  float M = fmaxf(fmaxf(m0, m1), fmaxf(m2, m3));
  float S = PS2[p0] * __expf(m0 - M) + PS2[p0 + 256] * __expf(m1 - M) +
            PS2[p0 + 512] * __expf(m2 - M) + PS2[p0 + 768] * __expf(m3 - M);
  Ssoft[(size_t)bI * K + k] = M + __logf(S);
  Shard[(size_t)bI * K + k] =
      fmaxf(fmaxf(PH2[p0], PH2[p0 + 256]), fmaxf(PH2[p0 + 512], PH2[p0 + 768]));
}

// ---------------- K5: focal CE per row/col of each 256x256 matrix ----------------
__global__ __launch_bounds__(256) void k_focal(const float* __restrict__ Sglob,
                                               const float* __restrict__ Ssoft,
                                               const float* __restrict__ Shard,
                                               float* __restrict__ misc) {
  int job = blockIdx.y;   // 0..5: {glob,globT,soft,softT,hard,hardT}
  int i = blockIdx.x;
  int t = threadIdx.x;
  const float* M = job < 2 ? Sglob : (job < 4 ? Ssoft : Shard);
  float v = (job & 1) ? M[(size_t)t * K + i] : M[(size_t)i * K + t];
  __shared__ float red[4];
  float mx = wave_reduce_max(v);
  if ((t & 63) == 0) red[t >> 6] = mx;
  __syncthreads();
  mx = fmaxf(fmaxf(red[0], red[1]), fmaxf(red[2], red[3]));
  __syncthreads();
  float sv = wave_reduce_sum(v);
  if ((t & 63) == 0) red[t >> 6] = sv;
  __syncthreads();
  float sumv = red[0] + red[1] + red[2] + red[3];
  __syncthreads();
  float se = wave_reduce_sum(expf(v - mx));
  if ((t & 63) == 0) red[t >> 6] = se;
  __syncthreads();
  if (t == 0) {
    float sumexp = red[0] + red[1] + red[2] + red[3];
    float logZ = mx + logf(sumexp);
    float diag = M[(size_t)i * K + i];
    float nll = logZ - diag;
    float smooth = logZ - sumv * (1.0f / 256.0f);
    float ce = 0.75f * nll + 0.25f * smooth;
    float pt = expf(-ce);
    float fo = (1.0f - pt) * (1.0f - pt) * ce;
    atomicAdd(&misc[1 + job], fo);
  }
}

// ---------------- K6: combine ----------------
__global__ void k_finish(const float* __restrict__ misc, float* __restrict__ out) {
  float lg = misc[1] + misc[2];
  float ls = misc[3] + misc[4];
  float lh = misc[5] + misc[6];
  out[0] = (0.2f * lg + 0.3f * ls + 0.5f * lh) * 0.5f * (1.0f / 256.0f);
}

extern "C" void kernel_launch(void* const* d_in, const int* in_sizes, int n_in,
                              void* d_out, int out_size, void* d_ws, size_t ws_size,
                              hipStream_t stream) {
  const float* yolo = (const float*)d_in[0];   // (B, C, N)
  const float* clip = (const float*)d_in[1];   // (B, C)
  const float* ls   = (const float*)d_in[2];   // (1,)
  float* out = (float*)d_out;
  float* ws = (float*)d_ws;
  unsigned short* clipnb = (unsigned short*)(ws + OFF_CLIPNB);
  float* invg  = ws + OFF_INV;
  float* U4    = ws + OFF_U4;
  float* PM2   = ws + OFF_PM;
  float* PS2   = ws + OFF_PS;
  float* PH2   = ws + OFF_PH;
  float* PG2   = ws + OFF_PG;
  float* Sglob = ws + OFF_SGLOB;
  float* Ssoft = ws + OFF_SSOFT;
  float* Shard = ws + OFF_SHARD;
  float* misc  = ws + OFF_MISC;

  k_misc<<<1, 64, 0, stream>>>(ls, misc);
  k_rownorm<<<256, 256, 0, stream>>>(clip, clipnb);
  k_inv<<<512, 512, 0, stream>>>(yolo, invg);
  k_main_mfma<<<512, 256, 0, stream>>>(yolo, clipnb, invg, misc, U4,
                                       PM2, PS2, PH2, PG2);
  k_post<<<256, 256, 0, stream>>>(U4, PG2, PM2, PS2, PH2, misc,
                                  Sglob, Ssoft, Shard);
  k_focal<<<dim3(256, 6), 256, 0, stream>>>(Sglob, Ssoft, Shard, misc);
  k_finish<<<1, 1, 0, stream>>>(misc, out);
}

// Round 3
// 476.077 us; speedup vs baseline: 1.1295x; 1.1295x over previous
//
#include <hip/hip_runtime.h>
#include <hip/hip_bf16.h>
#include <math.h>

// Problem constants
constexpr int B = 256;
constexpr int C = 512;
constexpr int N = 512;
constexpr int K = 256;   // = B

// ws layout (floats)
constexpr size_t OFF_CLIPNB = 0;                            // B*C bf16 = B*C/2 floats
constexpr size_t OFF_INV    = OFF_CLIPNB + (size_t)B*C/2;   // B*N
constexpr size_t OFF_PM     = OFF_INV    + (size_t)B*N;     // 1024 slots * K
constexpr size_t OFF_PS     = OFF_PM     + (size_t)1024*K;
constexpr size_t OFF_PH     = OFF_PS     + (size_t)1024*K;
constexpr size_t OFF_PG     = OFF_PH     + (size_t)1024*K;
constexpr size_t OFF_SGLOB  = OFF_PG     + (size_t)1024*K;  // B*K
constexpr size_t OFF_SSOFT  = OFF_SGLOB  + (size_t)B*K;
constexpr size_t OFF_SHARD  = OFF_SSOFT  + (size_t)B*K;
constexpr size_t OFF_GN     = OFF_SHARD  + (size_t)B*K;     // B (gsq accum)
constexpr size_t OFF_MISC   = OFF_GN     + (size_t)B;       // 7

typedef __attribute__((ext_vector_type(8))) short short8;
typedef __attribute__((ext_vector_type(4))) float f32x4;

__device__ __forceinline__ float wave_reduce_sum(float v) {
  #pragma unroll
  for (int off = 32; off > 0; off >>= 1) v += __shfl_xor(v, off, 64);
  return v;
}
__device__ __forceinline__ float wave_reduce_max(float v) {
  #pragma unroll
  for (int off = 32; off > 0; off >>= 1) v = fmaxf(v, __shfl_xor(v, off, 64));
  return v;
}
__device__ __forceinline__ unsigned int bf16_rne(float x) {
  unsigned int u = __builtin_bit_cast(unsigned int, x);
  return (u + 0x7FFFu + ((u >> 16) & 1u)) >> 16;
}
// pair-pack via hardware v_cvt_pk_bf16_f32 (RNE, same numerics as bf16_rne
// for finite inputs); union punning since __hip_bfloat162 is not
// trivially-copyable (bit_cast rejected).
__device__ __forceinline__ unsigned int pk2(float x, float y) {
  union { __hip_bfloat162 h; unsigned int u; } cv;
  cv.h = __float22bfloat162_rn(make_float2(x, y));
  return cv.u;
}

// ---------------- K0: scale + zero focal accumulators ----------------
__global__ void k_misc(const float* __restrict__ ls, float* __restrict__ misc) {
  int t = threadIdx.x;
  if (t == 0) misc[0] = fminf(fmaxf(expf(ls[0]), 0.01f), 100.0f);
  if (t >= 1 && t < 7) misc[t] = 0.0f;
}

// ---------------- K1: l2-normalize clip rows -> bf16; zero gsq ----------------
__global__ __launch_bounds__(256) void k_rownorm(const float* __restrict__ src,
                                                 unsigned short* __restrict__ dst_bf,
                                                 float* __restrict__ gsq) {
  int b = blockIdx.x, t = threadIdx.x;
  if (t == 0) gsq[b] = 0.0f;
  float x0 = src[(size_t)b * C + t];
  float x1 = src[(size_t)b * C + t + 256];
  __shared__ float red[4];
  float w = wave_reduce_sum(x0 * x0 + x1 * x1);
  if ((t & 63) == 0) red[t >> 6] = w;
  __syncthreads();
  float tot = red[0] + red[1] + red[2] + red[3];
  float r = 1.0f / fmaxf(sqrtf(tot), 1e-12f);
  dst_bf[(size_t)b * C + t] = (unsigned short)bf16_rne(x0 * r);
  dst_bf[(size_t)b * C + t + 256] = (unsigned short)bf16_rne(x1 * r);
}

// ---------------- K2: fused main GEMM (bf16 MFMA), pipelined ----------------
// grid 512: block bh -> b = bh>>1, half = bh&1.
// Round-0 structure (ssq/inv computed in-kernel during staging; raw-x staged
// as bf16; inv folded in epilogue) + pipeline fixes:
//  - xl double-buffered (2x16KB); ONE raw s_barrier per chunk with
//    lgkmcnt(0)-only drain -> global loads stay in flight across barrier+MFMA.
//  - yolo chunk cc+1 loads prefetched into registers pre-barrier; A-frags
//    (L2-hot) issued pre-barrier.
//  - pk2 pack via v_cvt_pk_bf16_f32 (pack VALU ~2.5x lower).
//  - per-window (m,s,h,g) partials to PM2/PS2/PH2/PG2 slots (no persistent
//    48-VGPR state); merged in k_post.
__global__ __launch_bounds__(256, 2) void k_main_mfma(
    const float* __restrict__ yolo,
    const unsigned short* __restrict__ clipnb,
    const float* __restrict__ misc,
    float* __restrict__ invg,
    float* __restrict__ PM2, float* __restrict__ PS2,
    float* __restrict__ PH2, float* __restrict__ PG2) {
  int bh = blockIdx.x;
  int b = bh >> 1, half = bh & 1;
  int t = threadIdx.x;
  int w = t >> 6, lane = t & 63;
  int quad = lane >> 4, col = lane & 15;

  __shared__ unsigned int xl[2][128 * 32];   // 2 x 16 KB, rotated rows
  __shared__ float ssqb[8 * 128];            // 4 KB
  __shared__ float invt[128];

  const float scale = misc[0];
  const float* ybase = yolo + (size_t)b * C * N;

  int nf = t & 31;                 // 4-n group (n = 4nf+j)
  int cp0 = t >> 5;                // 0..7 (c-pair subset)
  unsigned int rotv = (8u * (nf & 3) + 4u * (unsigned)(nf >> 2)) & 31u;

  #pragma unroll 1
  for (int iter = 0; iter < 2; iter++) {
    int n0 = half * 256 + iter * 128;

    f32x4 acc[4][8];
    #pragma unroll
    for (int kt = 0; kt < 4; kt++)
      #pragma unroll
      for (int nt = 0; nt < 8; nt++) {
        f32x4 z = {0.f, 0.f, 0.f, 0.f};
        acc[kt][nt] = z;
      }

    float4 ssq4 = {0.f, 0.f, 0.f, 0.f};

    // prologue: issue chunk-0 yolo loads
    float4 Ya[4], Yb[4];
    #pragma unroll
    for (int p = 0; p < 4; p++) {
      const float* pa = ybase + (size_t)(2 * (cp0 + 8 * p)) * N + n0 + 4 * nf;
      Ya[p] = *(const float4*)pa;
      Yb[p] = *(const float4*)(pa + N);
    }

    #pragma unroll
    for (int cc = 0; cc < 8; cc++) {
      unsigned int* xbuf = &xl[cc & 1][0];
      int c0 = cc * 64;

      // ---- pack chunk cc from registers: ssq accumulate + bf16 transpose ----
      #pragma unroll
      for (int p = 0; p < 4; p++) {
        ssq4.x += Ya[p].x * Ya[p].x + Yb[p].x * Yb[p].x;
        ssq4.y += Ya[p].y * Ya[p].y + Yb[p].y * Yb[p].y;
        ssq4.z += Ya[p].z * Ya[p].z + Yb[p].z * Yb[p].z;
        ssq4.w += Ya[p].w * Ya[p].w + Yb[p].w * Yb[p].w;
        unsigned int pos = ((unsigned)(cp0 + 8 * p) + rotv) & 31u;
        int base0 = (4 * nf) * 32;
        xbuf[base0 + pos]       = pk2(Ya[p].x, Yb[p].x);
        xbuf[base0 + 32 + pos]  = pk2(Ya[p].y, Yb[p].y);
        xbuf[base0 + 64 + pos]  = pk2(Ya[p].z, Yb[p].z);
        xbuf[base0 + 96 + pos]  = pk2(Ya[p].w, Yb[p].w);
      }

      // ---- issue NEXT chunk yolo loads (HBM) before the barrier ----
      if (cc < 7) {
        #pragma unroll
        for (int p = 0; p < 4; p++) {
          const float* pa =
              ybase + (size_t)((cc + 1) * 64 + 2 * (cp0 + 8 * p)) * N + n0 + 4 * nf;
          Ya[p] = *(const float4*)pa;
          Yb[p] = *(const float4*)(pa + N);
        }
      }
      // ---- A-frags for THIS chunk (L2-hot), also pre-barrier ----
      short8 afr[4][2];
      #pragma unroll
      for (int kt = 0; kt < 4; kt++)
        #pragma unroll
        for (int s = 0; s < 2; s++) {
          const unsigned short* ap =
              clipnb + (size_t)(64 * w + 16 * kt + col) * C + c0 + 32 * s + 8 * quad;
          union { uint4 u; short8 v; } fa;
          fa.u = *(const uint4*)ap;
          afr[kt][s] = fa.v;
        }

      // ---- barrier: drain LDS writes only; global loads stay in flight ----
      asm volatile("s_waitcnt lgkmcnt(0)" ::: "memory");
      __builtin_amdgcn_s_barrier();

      // ---- MFMA phase: b128 frag reads, conflict-free bank tiling ----
      #pragma unroll
      for (int s = 0; s < 2; s++) {
        #pragma unroll
        for (int nt = 0; nt < 8; nt++) {
          int n = 16 * nt + col;
          unsigned int pos =
              (unsigned)(16 * s + 4 * quad + 8 * (col >> 2) + 4 * nt) & 31u;
          union { uint4 u; short8 v; } fb;
          fb.u = *(const uint4*)&xbuf[n * 32 + pos];
          #pragma unroll
          for (int kt = 0; kt < 4; kt++)
            acc[kt][nt] = __builtin_amdgcn_mfma_f32_16x16x32_bf16(
                afr[kt][s], fb.v, acc[kt][nt], 0, 0, 0);
        }
      }
    }

    // ---- ssq reduce -> inv for this 128-n window ----
    *(float4*)&ssqb[cp0 * 128 + 4 * nf] = ssq4;
    __syncthreads();
    if (t < 128) {
      float s = 0.f;
      #pragma unroll
      for (int g = 0; g < 8; g++) s += ssqb[g * 128 + t];
      float iv = 1.0f / fmaxf(sqrtf(s), 1e-12f);
      invt[t] = iv;
      invg[(size_t)b * N + n0 + t] = iv;
    }
    __syncthreads();

    // ---- per-window epilogue: fold inv, online (m,s,h) + gsum, write slot ----
    float invn[8];
    #pragma unroll
    for (int nt = 0; nt < 8; nt++) invn[nt] = invt[16 * nt + col];
    size_t slot = (size_t)bh * 2 + iter;
    #pragma unroll
    for (int kt = 0; kt < 4; kt++)
      #pragma unroll
      for (int r = 0; r < 4; r++) {
        float mm = -1e30f, ss = 0.f, hh = -1e30f, gg = 0.f;
        #pragma unroll
        for (int nt = 0; nt < 8; nt++) {
          float vu = acc[kt][nt][r] * invn[nt];
          gg += vu;
          float v = vu * scale;
          hh = fmaxf(hh, v);
          float M = fmaxf(mm, v);
          ss = ss * __expf(mm - M) + __expf(v - M);
          mm = M;
        }
        #pragma unroll
        for (int o = 1; o < 16; o <<= 1) {
          float mo = __shfl_xor(mm, o, 64);
          float so = __shfl_xor(ss, o, 64);
          float ho = __shfl_xor(hh, o, 64);
          float go = __shfl_xor(gg, o, 64);
          float M = fmaxf(mm, mo);
          ss = ss * __expf(mm - M) + so * __expf(mo - M);
          mm = M;
          hh = fmaxf(hh, ho);
          gg += go;
        }
        if (col == 0) {
          int k = 64 * w + 16 * kt + 4 * quad + r;
          size_t a = slot * 256 + k;
          PM2[a] = mm; PS2[a] = ss; PH2[a] = hh; PG2[a] = gg;
        }
      }
  }
}

// ---------------- K3: gsq[b] += ||u_chalf||^2, u[c] = sum_n x[c][n]*inv[n] ----
// grid 512 = (b, c-half): 2 blocks/CU, 16 waves/CU; wave handles 32 c's
// (192 serial ds_swizzle per thread vs 384 before).
__global__ __launch_bounds__(512) void k_gnorm(const float* __restrict__ yolo,
                                               const float* __restrict__ invg,
                                               float* __restrict__ gsq) {
  int bc = blockIdx.x;
  int b = bc >> 1, ch = bc & 1;
  int t = threadIdx.x;
  int w = t >> 6, lane = t & 63;
  const float* xb = yolo + (size_t)b * C * N + (size_t)(ch * 256) * N;
  const float* ivb = invg + (size_t)b * N;
  float4 iv0 = *(const float4*)(ivb + 4 * lane);
  float4 iv1 = *(const float4*)(ivb + 256 + 4 * lane);
  float sq = 0.f;
  #pragma unroll 4
  for (int ci = 0; ci < 32; ci++) {
    const float* row = xb + (size_t)(w * 32 + ci) * N + 4 * lane;
    float4 v0 = *(const float4*)row;
    float4 v1 = *(const float4*)(row + 256);
    float cs = v0.x * iv0.x + v0.y * iv0.y + v0.z * iv0.z + v0.w * iv0.w +
               v1.x * iv1.x + v1.y * iv1.y + v1.z * iv1.z + v1.w * iv1.w;
    cs = wave_reduce_sum(cs);
    sq += cs * cs;      // identical on all lanes post-butterfly
  }
  __shared__ float red[8];
  if (lane == 0) red[w] = sq;
  __syncthreads();
  if (t == 0) {
    float s = 0.f;
    #pragma unroll
    for (int g = 0; g < 8; g++) s += red[g];
    atomicAdd(&gsq[b], s);
  }
}

// ---------------- K4: merge partials: gn, Sglob, Ssoft, Shard ----------------
// block = b; slots 4b..4b+3 hold (half,iter) window partials.
__global__ __launch_bounds__(256) void k_post(
    const float* __restrict__ PG2, const float* __restrict__ PM2,
    const float* __restrict__ PS2, const float* __restrict__ PH2,
    const float* __restrict__ gsq, const float* __restrict__ misc,
    float* __restrict__ Sglob, float* __restrict__ Ssoft,
    float* __restrict__ Shard) {
  int bI = blockIdx.x;
  int k = threadIdx.x;
  float gn = fmaxf(sqrtf(gsq[bI]) * (1.0f / (float)N), 1e-12f);
  size_t p0 = (size_t)bI * 4 * 256 + k;
  float g = PG2[p0] + PG2[p0 + 256] + PG2[p0 + 512] + PG2[p0 + 768];
  Sglob[(size_t)bI * K + k] = misc[0] * g * (1.0f / (float)N) / gn;
  float m0 = PM2[p0], m1 = PM2[p0 + 256], m2 = PM2[p0 + 512], m3 = PM2[p0 + 768];
  float M = fmaxf(fmaxf(m0, m1), fmaxf(m2, m3));
  float S = PS2[p0] * __expf(m0 - M) + PS2[p0 + 256] * __expf(m1 - M) +
            PS2[p0 + 512] * __expf(m2 - M) + PS2[p0 + 768] * __expf(m3 - M);
  Ssoft[(size_t)bI * K + k] = M + __logf(S);
  Shard[(size_t)bI * K + k] =
      fmaxf(fmaxf(PH2[p0], PH2[p0 + 256]), fmaxf(PH2[p0 + 512], PH2[p0 + 768]));
}

// ---------------- K5: focal CE per row/col of each 256x256 matrix ----------------
__global__ __launch_bounds__(256) void k_focal(const float* __restrict__ Sglob,
                                               const float* __restrict__ Ssoft,
                                               const float* __restrict__ Shard,
                                               float* __restrict__ misc) {
  int job = blockIdx.y;   // 0..5: {glob,globT,soft,softT,hard,hardT}
  int i = blockIdx.x;
  int t = threadIdx.x;
  const float* M = job < 2 ? Sglob : (job < 4 ? Ssoft : Shard);
  float v = (job & 1) ? M[(size_t)t * K + i] : M[(size_t)i * K + t];
  __shared__ float red[4];
  float mx = wave_reduce_max(v);
  if ((t & 63) == 0) red[t >> 6] = mx;
  __syncthreads();
  mx = fmaxf(fmaxf(red[0], red[1]), fmaxf(red[2], red[3]));
  __syncthreads();
  float sv = wave_reduce_sum(v);
  if ((t & 63) == 0) red[t >> 6] = sv;
  __syncthreads();
  float sumv = red[0] + red[1] + red[2] + red[3];
  __syncthreads();
  float se = wave_reduce_sum(expf(v - mx));
  if ((t & 63) == 0) red[t >> 6] = se;
  __syncthreads();
  if (t == 0) {
    float sumexp = red[0] + red[1] + red[2] + red[3];
    float logZ = mx + logf(sumexp);
    float diag = M[(size_t)i * K + i];
    float nll = logZ - diag;
    float smooth = logZ - sumv * (1.0f / 256.0f);
    float ce = 0.75f * nll + 0.25f * smooth;
    float pt = expf(-ce);
    float fo = (1.0f - pt) * (1.0f - pt) * ce;
    atomicAdd(&misc[1 + job], fo);
  }
}

// ---------------- K6: combine ----------------
__global__ void k_finish(const float* __restrict__ misc, float* __restrict__ out) {
  float lg = misc[1] + misc[2];
  float ls = misc[3] + misc[4];
  float lh = misc[5] + misc[6];
  out[0] = (0.2f * lg + 0.3f * ls + 0.5f * lh) * 0.5f * (1.0f / 256.0f);
}

extern "C" void kernel_launch(void* const* d_in, const int* in_sizes, int n_in,
                              void* d_out, int out_size, void* d_ws, size_t ws_size,
                              hipStream_t stream) {
  const float* yolo = (const float*)d_in[0];   // (B, C, N)
  const float* clip = (const float*)d_in[1];   // (B, C)
  const float* ls   = (const float*)d_in[2];   // (1,)
  float* out = (float*)d_out;
  float* ws = (float*)d_ws;
  unsigned short* clipnb = (unsigned short*)(ws + OFF_CLIPNB);
  float* invg  = ws + OFF_INV;
  float* PM2   = ws + OFF_PM;
  float* PS2   = ws + OFF_PS;
  float* PH2   = ws + OFF_PH;
  float* PG2   = ws + OFF_PG;
  float* Sglob = ws + OFF_SGLOB;
  float* Ssoft = ws + OFF_SSOFT;
  float* Shard = ws + OFF_SHARD;
  float* gsq   = ws + OFF_GN;
  float* misc  = ws + OFF_MISC;

  k_misc<<<1, 64, 0, stream>>>(ls, misc);
  k_rownorm<<<256, 256, 0, stream>>>(clip, clipnb, gsq);
  k_main_mfma<<<512, 256, 0, stream>>>(yolo, clipnb, misc, invg,
                                       PM2, PS2, PH2, PG2);
  k_gnorm<<<512, 512, 0, stream>>>(yolo, invg, gsq);
  k_post<<<256, 256, 0, stream>>>(PG2, PM2, PS2, PH2, gsq, misc,
                                  Sglob, Ssoft, Shard);
  k_focal<<<dim3(256, 6), 256, 0, stream>>>(Sglob, Ssoft, Shard, misc);
  k_finish<<<1, 1, 0, stream>>>(misc, out);
}

// Round 4
// 430.011 us; speedup vs baseline: 1.2505x; 1.1071x over previous
//
#include <hip/hip_runtime.h>
#include <hip/hip_bf16.h>
#include <math.h>

// Problem constants
constexpr int B = 256;
constexpr int C = 512;
constexpr int N = 512;
constexpr int K = 256;   // = B
constexpr int NWIN = 8;  // 64-n windows per b
constexpr int NSLOT = B * NWIN;  // 2048

// ws layout (floats)
constexpr size_t OFF_CLIPNB = 0;                              // B*C bf16 = B*C/2 floats
constexpr size_t OFF_U      = OFF_CLIPNB + (size_t)B*C/2;     // NSLOT*C
constexpr size_t OFF_PM     = OFF_U      + (size_t)NSLOT*C;   // NSLOT*K each
constexpr size_t OFF_PS     = OFF_PM     + (size_t)NSLOT*K;
constexpr size_t OFF_PH     = OFF_PS     + (size_t)NSLOT*K;
constexpr size_t OFF_PG     = OFF_PH     + (size_t)NSLOT*K;
constexpr size_t OFF_SGLOB  = OFF_PG     + (size_t)NSLOT*K;   // B*K
constexpr size_t OFF_SSOFT  = OFF_SGLOB  + (size_t)B*K;
constexpr size_t OFF_SHARD  = OFF_SSOFT  + (size_t)B*K;
constexpr size_t OFF_MISC   = OFF_SHARD  + (size_t)B*K;       // 7

typedef __attribute__((ext_vector_type(8))) short short8;
typedef __attribute__((ext_vector_type(4))) float f32x4;

__device__ __forceinline__ float wave_reduce_sum(float v) {
  #pragma unroll
  for (int off = 32; off > 0; off >>= 1) v += __shfl_xor(v, off, 64);
  return v;
}
__device__ __forceinline__ float wave_reduce_max(float v) {
  #pragma unroll
  for (int off = 32; off > 0; off >>= 1) v = fmaxf(v, __shfl_xor(v, off, 64));
  return v;
}
__device__ __forceinline__ unsigned int bf16_rne(float x) {
  unsigned int u = __builtin_bit_cast(unsigned int, x);
  return (u + 0x7FFFu + ((u >> 16) & 1u)) >> 16;
}
// pair-pack via hardware v_cvt_pk_bf16_f32 (RNE); union punning since
// __hip_bfloat162 is not trivially copyable.
__device__ __forceinline__ unsigned int pk2(float x, float y) {
  union { __hip_bfloat162 h; unsigned int u; } cv;
  cv.h = __float22bfloat162_rn(make_float2(x, y));
  return cv.u;
}

// ---------------- K0: scale + zero focal accumulators ----------------
__global__ void k_misc(const float* __restrict__ ls, float* __restrict__ misc) {
  int t = threadIdx.x;
  if (t == 0) misc[0] = fminf(fmaxf(expf(ls[0]), 0.01f), 100.0f);
  if (t >= 1 && t < 7) misc[t] = 0.0f;
}

// ---------------- K1: l2-normalize clip rows -> bf16 ----------------
__global__ __launch_bounds__(256) void k_rownorm(const float* __restrict__ src,
                                                 unsigned short* __restrict__ dst_bf) {
  int b = blockIdx.x, t = threadIdx.x;
  float x0 = src[(size_t)b * C + t];
  float x1 = src[(size_t)b * C + t + 256];
  __shared__ float red[4];
  float w = wave_reduce_sum(x0 * x0 + x1 * x1);
  if ((t & 63) == 0) red[t >> 6] = w;
  __syncthreads();
  float tot = red[0] + red[1] + red[2] + red[3];
  float r = 1.0f / fmaxf(sqrtf(tot), 1e-12f);
  dst_bf[(size_t)b * C + t] = (unsigned short)bf16_rne(x0 * r);
  dst_bf[(size_t)b * C + t + 256] = (unsigned short)bf16_rne(x1 * r);
}

// ---------------- K2: fused main GEMM (bf16 MFMA), single yolo pass ----------
// grid 2048: block bw -> b = bw>>3, win = bw&7 (n in [64*win, 64*win+64)).
// The ENTIRE 64n x 512c bf16 tile is persistent in LDS (64 KB). After all 8
// c-chunks: ssq -> inv in-block, then u[c] = sum_n x_bf16[c][n]*inv[n] read
// straight from the LDS tile -> k_gnorm's 256 MB global re-read is DELETED.
// Chunk regions are disjoint -> no double buffer; one lgkm-only barrier per
// chunk (global prefetch stays in flight). 2-chunk-deep yolo prefetch
// (acc halved to 64 VGPR frees the registers).
// LDS row n = 256 dwords (full C as bf16 pairs); within each 32-dword chunk
// segment, dword cp stored at (cp + rot(n)) & 31, rot(n)=8*((n>>2)&3)+4*(n>>4):
//  - MFMA b128 frag reads: exactly 8 bank-touches/bank (optimal)
//  - staging b32 writes: 2-way conflict (free)
//  - u-epilogue column walk: 2-way conflict (free)
__global__ __launch_bounds__(256, 2) void k_main_mfma(
    const float* __restrict__ yolo,
    const unsigned short* __restrict__ clipnb,
    const float* __restrict__ misc,
    float* __restrict__ U,
    float* __restrict__ PM2, float* __restrict__ PS2,
    float* __restrict__ PH2, float* __restrict__ PG2) {
  int bw = blockIdx.x;
  int b = bw >> 3, win = bw & 7;
  int n0 = win * 64;
  int t = threadIdx.x;
  int w = t >> 6, lane = t & 63;
  int quad = lane >> 4, col = lane & 15;

  __shared__ unsigned int xl[64 * 256];   // 64 KB persistent tile
  __shared__ float ssqb[16 * 64];         // 4 KB
  __shared__ float invt[64];

  const float scale = misc[0];
  const float* ybase = yolo + (size_t)b * C * N + n0;

  int nf = t & 15;                 // n-group: n = 4*nf + j
  int cp0 = t >> 4;                // 0..15 (c-pair subset)
  unsigned int rotv = (8u * (nf & 3) + 4u * (unsigned)(nf >> 2)) & 31u;

  f32x4 acc[4][4];
  #pragma unroll
  for (int kt = 0; kt < 4; kt++)
    #pragma unroll
    for (int nt = 0; nt < 4; nt++) {
      f32x4 z = {0.f, 0.f, 0.f, 0.f};
      acc[kt][nt] = z;
    }

  float4 ssq4 = {0.f, 0.f, 0.f, 0.f};

  // prologue: load chunks 0 and 1 (2-deep prefetch)
  float4 Ya[2][2], Yb[2][2];
  #pragma unroll
  for (int q = 0; q < 2; q++)
    #pragma unroll
    for (int p = 0; p < 2; p++) {
      const float* pa = ybase + (size_t)(q * 64 + 2 * (cp0 + 16 * p)) * N + 4 * nf;
      Ya[q][p] = *(const float4*)pa;
      Yb[q][p] = *(const float4*)(pa + N);
    }

  #pragma unroll
  for (int cc = 0; cc < 8; cc++) {
    int c0 = cc * 64;
    int par = cc & 1;

    // ---- pack chunk cc from registers: ssq accumulate + bf16 transpose ----
    #pragma unroll
    for (int p = 0; p < 2; p++) {
      float4 a = Ya[par][p], bb = Yb[par][p];
      ssq4.x += a.x * a.x + bb.x * bb.x;
      ssq4.y += a.y * a.y + bb.y * bb.y;
      ssq4.z += a.z * a.z + bb.z * bb.z;
      ssq4.w += a.w * a.w + bb.w * bb.w;
      unsigned int pos = ((unsigned)(cp0 + 16 * p) + rotv) & 31u;
      int base0 = (4 * nf) * 256 + cc * 32;
      xl[base0 + pos]        = pk2(a.x, bb.x);
      xl[base0 + 256 + pos]  = pk2(a.y, bb.y);
      xl[base0 + 512 + pos]  = pk2(a.z, bb.z);
      xl[base0 + 768 + pos]  = pk2(a.w, bb.w);
    }

    // ---- prefetch chunk cc+2 (HBM), issued before the barrier ----
    if (cc < 6) {
      #pragma unroll
      for (int p = 0; p < 2; p++) {
        const float* pa =
            ybase + (size_t)((cc + 2) * 64 + 2 * (cp0 + 16 * p)) * N + 4 * nf;
        Ya[par][p] = *(const float4*)pa;
        Yb[par][p] = *(const float4*)(pa + N);
      }
    }

    // ---- A-frags for THIS chunk (L2-hot), also pre-barrier ----
    short8 afr[4][2];
    #pragma unroll
    for (int kt = 0; kt < 4; kt++)
      #pragma unroll
      for (int s = 0; s < 2; s++) {
        const unsigned short* ap =
            clipnb + (size_t)(64 * w + 16 * kt + col) * C + c0 + 32 * s + 8 * quad;
        union { uint4 u; short8 v; } fa;
        fa.u = *(const uint4*)ap;
        afr[kt][s] = fa.v;
      }

    // ---- barrier: drain LDS writes only; global loads stay in flight ----
    asm volatile("s_waitcnt lgkmcnt(0)" ::: "memory");
    __builtin_amdgcn_s_barrier();

    // ---- MFMA phase: b128 frag reads, optimal bank tiling ----
    #pragma unroll
    for (int s = 0; s < 2; s++) {
      #pragma unroll
      for (int nt = 0; nt < 4; nt++) {
        int n = 16 * nt + col;
        unsigned int pos =
            (unsigned)(16 * s + 4 * quad + 8 * (col >> 2) + 4 * nt) & 31u;
        union { uint4 u; short8 v; } fb;
        fb.u = *(const uint4*)&xl[n * 256 + cc * 32 + pos];
        #pragma unroll
        for (int kt = 0; kt < 4; kt++)
          acc[kt][nt] = __builtin_amdgcn_mfma_f32_16x16x32_bf16(
              afr[kt][s], fb.v, acc[kt][nt], 0, 0, 0);
      }
    }
  }

  // ---- ssq reduce -> inv for this 64-n window ----
  *(float4*)&ssqb[cp0 * 64 + 4 * nf] = ssq4;
  __syncthreads();
  if (t < 64) {
    float s = 0.f;
    #pragma unroll
    for (int g = 0; g < 16; g++) s += ssqb[g * 64 + t];
    invt[t] = 1.0f / fmaxf(sqrtf(s), 1e-12f);
  }
  __syncthreads();

  // ---- u-epilogue: u[c] = sum_n x_bf16[c][n]*inv[n], from the LDS tile ----
  {
    int chU = t >> 5, cl = t & 31;    // thread owns c-pair t (c = 2t, 2t+1)
    float u0 = 0.f, u1 = 0.f;
    #pragma unroll
    for (int n = 0; n < 64; n++) {
      unsigned int d =
          xl[n * 256 + chU * 32 + ((cl + 8 * ((n >> 2) & 3) + 4 * (n >> 4)) & 31)];
      float iv = invt[n];
      union { unsigned int u; float f; } lo, hi;
      lo.u = d << 16;
      hi.u = d & 0xFFFF0000u;
      u0 += lo.f * iv;
      u1 += hi.f * iv;
    }
    *(float2*)&U[(size_t)bw * C + 2 * t] = make_float2(u0, u1);
  }

  // ---- acc epilogue: fold inv, online (m,s,h) + gsum, write window slot ----
  float invn[4];
  #pragma unroll
  for (int nt = 0; nt < 4; nt++) invn[nt] = invt[16 * nt + col];
  #pragma unroll
  for (int kt = 0; kt < 4; kt++)
    #pragma unroll
    for (int r = 0; r < 4; r++) {
      float mm = -1e30f, ss = 0.f, hh = -1e30f, gg = 0.f;
      #pragma unroll
      for (int nt = 0; nt < 4; nt++) {
        float vu = acc[kt][nt][r] * invn[nt];
        gg += vu;
        float v = vu * scale;
        hh = fmaxf(hh, v);
        float M = fmaxf(mm, v);
        ss = ss * __expf(mm - M) + __expf(v - M);
        mm = M;
      }
      #pragma unroll
      for (int o = 1; o < 16; o <<= 1) {
        float mo = __shfl_xor(mm, o, 64);
        float so = __shfl_xor(ss, o, 64);
        float ho = __shfl_xor(hh, o, 64);
        float go = __shfl_xor(gg, o, 64);
        float M = fmaxf(mm, mo);
        ss = ss * __expf(mm - M) + so * __expf(mo - M);
        mm = M;
        hh = fmaxf(hh, ho);
        gg += go;
      }
      if (col == 0) {
        int k = 64 * w + 16 * kt + 4 * quad + r;
        size_t a = (size_t)bw * 256 + k;
        PM2[a] = mm; PS2[a] = ss; PH2[a] = hh; PG2[a] = gg;
      }
    }
}

// ---------------- K3: merge window partials: gn, Sglob, Ssoft, Shard --------
// block = b; slots 8b..8b+7 hold the 8 n-window partials.
__global__ __launch_bounds__(256) void k_post(
    const float* __restrict__ U, const float* __restrict__ PG2,
    const float* __restrict__ PM2, const float* __restrict__ PS2,
    const float* __restrict__ PH2, const float* __restrict__ misc,
    float* __restrict__ Sglob, float* __restrict__ Ssoft,
    float* __restrict__ Shard) {
  int bI = blockIdx.x;
  int t = threadIdx.x;
  __shared__ float red[4];
  __shared__ float gnS;
  // gn[b] = max(||u||/N, eps), u[c] = sum of 8 window partials
  float sq = 0.f;
  #pragma unroll
  for (int half = 0; half < 2; half++) {
    int c = t + 256 * half;
    float u = 0.f;
    #pragma unroll
    for (int j = 0; j < 8; j++) u += U[((size_t)bI * 8 + j) * C + c];
    sq += u * u;
  }
  float wsum = wave_reduce_sum(sq);
  if ((t & 63) == 0) red[t >> 6] = wsum;
  __syncthreads();
  if (t == 0) {
    float s = red[0] + red[1] + red[2] + red[3];
    gnS = fmaxf(sqrtf(s) * (1.0f / (float)N), 1e-12f);
  }
  __syncthreads();
  float gn = gnS;
  int k = t;
  size_t p0 = (size_t)bI * 8 * 256 + k;
  float g = 0.f;
  #pragma unroll
  for (int j = 0; j < 8; j++) g += PG2[p0 + j * 256];
  Sglob[(size_t)bI * K + k] = misc[0] * g * (1.0f / (float)N) / gn;
  float M = -1e30f;
  #pragma unroll
  for (int j = 0; j < 8; j++) M = fmaxf(M, PM2[p0 + j * 256]);
  float S = 0.f;
  #pragma unroll
  for (int j = 0; j < 8; j++) S += PS2[p0 + j * 256] * __expf(PM2[p0 + j * 256] - M);
  Ssoft[(size_t)bI * K + k] = M + __logf(S);
  float H = -1e30f;
  #pragma unroll
  for (int j = 0; j < 8; j++) H = fmaxf(H, PH2[p0 + j * 256]);
  Shard[(size_t)bI * K + k] = H;
}

// ---------------- K4: focal CE per row/col of each 256x256 matrix -----------
__global__ __launch_bounds__(256) void k_focal(const float* __restrict__ Sglob,
                                               const float* __restrict__ Ssoft,
                                               const float* __restrict__ Shard,
                                               float* __restrict__ misc) {
  int job = blockIdx.y;   // 0..5: {glob,globT,soft,softT,hard,hardT}
  int i = blockIdx.x;
  int t = threadIdx.x;
  const float* M = job < 2 ? Sglob : (job < 4 ? Ssoft : Shard);
  float v = (job & 1) ? M[(size_t)t * K + i] : M[(size_t)i * K + t];
  __shared__ float red[4];
  float mx = wave_reduce_max(v);
  if ((t & 63) == 0) red[t >> 6] = mx;
  __syncthreads();
  mx = fmaxf(fmaxf(red[0], red[1]), fmaxf(red[2], red[3]));
  __syncthreads();
  float sv = wave_reduce_sum(v);
  if ((t & 63) == 0) red[t >> 6] = sv;
  __syncthreads();
  float sumv = red[0] + red[1] + red[2] + red[3];
  __syncthreads();
  float se = wave_reduce_sum(expf(v - mx));
  if ((t & 63) == 0) red[t >> 6] = se;
  __syncthreads();
  if (t == 0) {
    float sumexp = red[0] + red[1] + red[2] + red[3];
    float logZ = mx + logf(sumexp);
    float diag = M[(size_t)i * K + i];
    float nll = logZ - diag;
    float smooth = logZ - sumv * (1.0f / 256.0f);
    float ce = 0.75f * nll + 0.25f * smooth;
    float pt = expf(-ce);
    float fo = (1.0f - pt) * (1.0f - pt) * ce;
    atomicAdd(&misc[1 + job], fo);
  }
}

// ---------------- K5: combine ----------------
__global__ void k_finish(const float* __restrict__ misc, float* __restrict__ out) {
  float lg = misc[1] + misc[2];
  float ls = misc[3] + misc[4];
  float lh = misc[5] + misc[6];
  out[0] = (0.2f * lg + 0.3f * ls + 0.5f * lh) * 0.5f * (1.0f / 256.0f);
}

extern "C" void kernel_launch(void* const* d_in, const int* in_sizes, int n_in,
                              void* d_out, int out_size, void* d_ws, size_t ws_size,
                              hipStream_t stream) {
  const float* yolo = (const float*)d_in[0];   // (B, C, N)
  const float* clip = (const float*)d_in[1];   // (B, C)
  const float* ls   = (const float*)d_in[2];   // (1,)
  float* out = (float*)d_out;
  float* ws = (float*)d_ws;
  unsigned short* clipnb = (unsigned short*)(ws + OFF_CLIPNB);
  float* U     = ws + OFF_U;
  float* PM2   = ws + OFF_PM;
  float* PS2   = ws + OFF_PS;
  float* PH2   = ws + OFF_PH;
  float* PG2   = ws + OFF_PG;
  float* Sglob = ws + OFF_SGLOB;
  float* Ssoft = ws + OFF_SSOFT;
  float* Shard = ws + OFF_SHARD;
  float* misc  = ws + OFF_MISC;

  k_misc<<<1, 64, 0, stream>>>(ls, misc);
  k_rownorm<<<256, 256, 0, stream>>>(clip, clipnb);
  k_main_mfma<<<NSLOT, 256, 0, stream>>>(yolo, clipnb, misc, U,
                                         PM2, PS2, PH2, PG2);
  k_post<<<256, 256, 0, stream>>>(U, PG2, PM2, PS2, PH2, misc,
                                  Sglob, Ssoft, Shard);
  k_focal<<<dim3(256, 6), 256, 0, stream>>>(Sglob, Ssoft, Shard, misc);
  k_finish<<<1, 1, 0, stream>>>(misc, out);
}

// Round 5
// 416.580 us; speedup vs baseline: 1.2908x; 1.0322x over previous
//
#include <hip/hip_runtime.h>
#include <hip/hip_bf16.h>
#include <math.h>

// Problem constants
constexpr int B = 256;
constexpr int C = 512;
constexpr int N = 512;
constexpr int K = 256;   // = B
constexpr int NWIN = 8;  // 64-n windows per b
constexpr int NSLOT = B * NWIN;  // 2048

// ws layout (floats)
constexpr size_t OFF_CLIPNB = 0;                              // B*C bf16 = B*C/2 floats
constexpr size_t OFF_U      = OFF_CLIPNB + (size_t)B*C/2;     // NSLOT*C
constexpr size_t OFF_PM     = OFF_U      + (size_t)NSLOT*C;   // NSLOT*K each
constexpr size_t OFF_PS     = OFF_PM     + (size_t)NSLOT*K;
constexpr size_t OFF_PH     = OFF_PS     + (size_t)NSLOT*K;
constexpr size_t OFF_PG     = OFF_PH     + (size_t)NSLOT*K;
constexpr size_t OFF_SGLOB  = OFF_PG     + (size_t)NSLOT*K;   // B*K
constexpr size_t OFF_SSOFT  = OFF_SGLOB  + (size_t)B*K;
constexpr size_t OFF_SHARD  = OFF_SSOFT  + (size_t)B*K;
constexpr size_t OFF_MISC   = OFF_SHARD  + (size_t)B*K;       // 7

typedef __attribute__((ext_vector_type(8))) short short8;
typedef __attribute__((ext_vector_type(4))) float f32x4;

__device__ __forceinline__ float wave_reduce_sum(float v) {
  #pragma unroll
  for (int off = 32; off > 0; off >>= 1) v += __shfl_xor(v, off, 64);
  return v;
}
__device__ __forceinline__ float wave_reduce_max(float v) {
  #pragma unroll
  for (int off = 32; off > 0; off >>= 1) v = fmaxf(v, __shfl_xor(v, off, 64));
  return v;
}
__device__ __forceinline__ unsigned int bf16_rne(float x) {
  unsigned int u = __builtin_bit_cast(unsigned int, x);
  return (u + 0x7FFFu + ((u >> 16) & 1u)) >> 16;
}
// pair-pack via hardware v_cvt_pk_bf16_f32 (RNE); union punning since
// __hip_bfloat162 is not trivially copyable.
__device__ __forceinline__ unsigned int pk2(float x, float y) {
  union { __hip_bfloat162 h; unsigned int u; } cv;
  cv.h = __float22bfloat162_rn(make_float2(x, y));
  return cv.u;
}

// ---------------- K1: l2-normalize clip rows -> bf16 (+ misc init) ----------
__global__ __launch_bounds__(256) void k_rownorm(const float* __restrict__ src,
                                                 const float* __restrict__ ls,
                                                 unsigned short* __restrict__ dst_bf,
                                                 float* __restrict__ misc) {
  int b = blockIdx.x, t = threadIdx.x;
  if (b == 0 && t < 7) {
    if (t == 0) misc[0] = fminf(fmaxf(expf(ls[0]), 0.01f), 100.0f);
    else misc[t] = 0.0f;
  }
  float x0 = src[(size_t)b * C + t];
  float x1 = src[(size_t)b * C + t + 256];
  __shared__ float red[4];
  float w = wave_reduce_sum(x0 * x0 + x1 * x1);
  if ((t & 63) == 0) red[t >> 6] = w;
  __syncthreads();
  float tot = red[0] + red[1] + red[2] + red[3];
  float r = 1.0f / fmaxf(sqrtf(tot), 1e-12f);
  dst_bf[(size_t)b * C + t] = (unsigned short)bf16_rne(x0 * r);
  dst_bf[(size_t)b * C + t + 256] = (unsigned short)bf16_rne(x1 * r);
}

// ---------------- K2: fused main GEMM (bf16 MFMA), single yolo pass ----------
// grid 2048: block bw -> b = bw>>3, win = bw&7 (n in [64*win, 64*win+64)).
// 512 threads = 8 waves; wave w owns k in [32w, 32w+32) (kt=2 tiles).
// 64 KB persistent 64n x 512c bf16 tile -> 2 blocks/CU = 16 waves/CU (2x the
// prior TLP; the per-chunk barrier drain is covered by the co-resident block
// and the 4-waves/SIMD within each block).
// After the 8 c-chunks: ssq -> inv in-block; u[c] = sum_n x_bf16[c][n]*inv[n]
// computed from the LDS tile (single yolo pass total).
// LDS row n = 256 dwords; within each 32-dword chunk segment, dword cp stored
// at (cp + rot(n)) & 31, rot(n)=8*((n>>2)&3)+4*(n>>4):
//  - MFMA b128 frag reads: exactly 8 bank-touches/bank (optimal)
//  - staging b32 writes / u-epilogue column walk: 2-way conflict (free)
__global__ __launch_bounds__(512, 4) void k_main_mfma(
    const float* __restrict__ yolo,
    const unsigned short* __restrict__ clipnb,
    const float* __restrict__ misc,
    float* __restrict__ U,
    float* __restrict__ PM2, float* __restrict__ PS2,
    float* __restrict__ PH2, float* __restrict__ PG2) {
  int bw = blockIdx.x;
  int b = bw >> 3, win = bw & 7;
  int n0 = win * 64;
  int t = threadIdx.x;
  int w = t >> 6, lane = t & 63;
  int quad = lane >> 4, col = lane & 15;

  __shared__ unsigned int xl[64 * 256];   // 64 KB persistent tile
  __shared__ float ssqb[32 * 64];         // 8 KB (reused as u-partials)
  __shared__ float invt[64];

  const float scale = misc[0];
  const float* ybase = yolo + (size_t)b * C * N + n0;

  int nf = t & 15;                 // n-group: n = 4*nf + j
  int cp = t >> 4;                 // 0..31 (c-pair within chunk)
  unsigned int rotv = (8u * (nf & 3) + 4u * (unsigned)(nf >> 2)) & 31u;

  f32x4 acc[2][4];
  #pragma unroll
  for (int kt = 0; kt < 2; kt++)
    #pragma unroll
    for (int nt = 0; nt < 4; nt++) {
      f32x4 z = {0.f, 0.f, 0.f, 0.f};
      acc[kt][nt] = z;
    }

  float4 ssq4 = {0.f, 0.f, 0.f, 0.f};

  // prologue: load chunks 0 and 1 (2-deep prefetch); 2 float4 per chunk
  float4 Ya[2], Yb[2];
  #pragma unroll
  for (int q = 0; q < 2; q++) {
    const float* pa = ybase + (size_t)(q * 64 + 2 * cp) * N + 4 * nf;
    Ya[q] = *(const float4*)pa;
    Yb[q] = *(const float4*)(pa + N);
  }

  #pragma unroll
  for (int cc = 0; cc < 8; cc++) {
    int c0 = cc * 64;
    int par = cc & 1;

    // ---- pack chunk cc from registers: ssq accumulate + bf16 transpose ----
    {
      float4 a = Ya[par], bb = Yb[par];
      ssq4.x += a.x * a.x + bb.x * bb.x;
      ssq4.y += a.y * a.y + bb.y * bb.y;
      ssq4.z += a.z * a.z + bb.z * bb.z;
      ssq4.w += a.w * a.w + bb.w * bb.w;
      unsigned int pos = ((unsigned)cp + rotv) & 31u;
      int base0 = (4 * nf) * 256 + cc * 32;
      xl[base0 + pos]        = pk2(a.x, bb.x);
      xl[base0 + 256 + pos]  = pk2(a.y, bb.y);
      xl[base0 + 512 + pos]  = pk2(a.z, bb.z);
      xl[base0 + 768 + pos]  = pk2(a.w, bb.w);
    }

    // ---- prefetch chunk cc+2 (HBM), issued before the barrier ----
    if (cc < 6) {
      const float* pa = ybase + (size_t)((cc + 2) * 64 + 2 * cp) * N + 4 * nf;
      Ya[par] = *(const float4*)pa;
      Yb[par] = *(const float4*)(pa + N);
    }

    // ---- A-frags for THIS chunk (L2-hot), also pre-barrier ----
    short8 afr[2][2];
    #pragma unroll
    for (int kt = 0; kt < 2; kt++)
      #pragma unroll
      for (int s = 0; s < 2; s++) {
        const unsigned short* ap =
            clipnb + (size_t)(32 * w + 16 * kt + col) * C + c0 + 32 * s + 8 * quad;
        union { uint4 u; short8 v; } fa;
        fa.u = *(const uint4*)ap;
        afr[kt][s] = fa.v;
      }

    // ---- barrier: drain LDS writes only; global loads stay in flight ----
    asm volatile("s_waitcnt lgkmcnt(0)" ::: "memory");
    __builtin_amdgcn_s_barrier();

    // ---- MFMA phase: b128 frag reads, optimal bank tiling ----
    #pragma unroll
    for (int s = 0; s < 2; s++) {
      #pragma unroll
      for (int nt = 0; nt < 4; nt++) {
        int n = 16 * nt + col;
        unsigned int pos =
            (unsigned)(16 * s + 4 * quad + 8 * (col >> 2) + 4 * nt) & 31u;
        union { uint4 u; short8 v; } fb;
        fb.u = *(const uint4*)&xl[n * 256 + cc * 32 + pos];
        #pragma unroll
        for (int kt = 0; kt < 2; kt++)
          acc[kt][nt] = __builtin_amdgcn_mfma_f32_16x16x32_bf16(
              afr[kt][s], fb.v, acc[kt][nt], 0, 0, 0);
      }
    }
  }

  // ---- ssq reduce -> inv for this 64-n window ----
  *(float4*)&ssqb[cp * 64 + 4 * nf] = ssq4;
  __syncthreads();
  if (t < 64) {
    float s = 0.f;
    #pragma unroll
    for (int g = 0; g < 32; g++) s += ssqb[g * 64 + t];
    invt[t] = 1.0f / fmaxf(sqrtf(s), 1e-12f);
  }
  __syncthreads();

  // ---- u-epilogue: u[c] = sum_n x_bf16[c][n]*inv[n], from the LDS tile ----
  // thread (th = t&255) owns c-pair th; nh = t>>8 splits the n-range.
  {
    int th = t & 255, nh = t >> 8;
    int ccU = th >> 5, clU = th & 31;
    float u0 = 0.f, u1 = 0.f;
    #pragma unroll
    for (int nn = 0; nn < 32; nn++) {
      int n = nh * 32 + nn;
      unsigned int d =
          xl[n * 256 + ccU * 32 + ((clU + 8 * ((n >> 2) & 3) + 4 * (n >> 4)) & 31)];
      float iv = invt[n];
      union { unsigned int u; float f; } lo, hi;
      lo.u = d << 16;
      hi.u = d & 0xFFFF0000u;
      u0 += lo.f * iv;
      u1 += hi.f * iv;
    }
    // reuse ssqb as u-partial buffer: [nh][th][2]
    ssqb[nh * 512 + th * 2]     = u0;
    ssqb[nh * 512 + th * 2 + 1] = u1;
  }
  __syncthreads();
  if (t < 256) {
    float u0 = ssqb[t * 2]     + ssqb[512 + t * 2];
    float u1 = ssqb[t * 2 + 1] + ssqb[512 + t * 2 + 1];
    *(float2*)&U[(size_t)bw * C + 2 * t] = make_float2(u0, u1);
  }

  // ---- acc epilogue: fold inv, online (m,s,h) + gsum, write window slot ----
  float invn[4];
  #pragma unroll
  for (int nt = 0; nt < 4; nt++) invn[nt] = invt[16 * nt + col];
  #pragma unroll
  for (int kt = 0; kt < 2; kt++)
    #pragma unroll
    for (int r = 0; r < 4; r++) {
      float mm = -1e30f, ss = 0.f, hh = -1e30f, gg = 0.f;
      #pragma unroll
      for (int nt = 0; nt < 4; nt++) {
        float vu = acc[kt][nt][r] * invn[nt];
        gg += vu;
        float v = vu * scale;
        hh = fmaxf(hh, v);
        float M = fmaxf(mm, v);
        ss = ss * __expf(mm - M) + __expf(v - M);
        mm = M;
      }
      #pragma unroll
      for (int o = 1; o < 16; o <<= 1) {
        float mo = __shfl_xor(mm, o, 64);
        float so = __shfl_xor(ss, o, 64);
        float ho = __shfl_xor(hh, o, 64);
        float go = __shfl_xor(gg, o, 64);
        float M = fmaxf(mm, mo);
        ss = ss * __expf(mm - M) + so * __expf(mo - M);
        mm = M;
        hh = fmaxf(hh, ho);
        gg += go;
      }
      if (col == 0) {
        int k = 32 * w + 16 * kt + 4 * quad + r;
        size_t a = (size_t)bw * 256 + k;
        PM2[a] = mm; PS2[a] = ss; PH2[a] = hh; PG2[a] = gg;
      }
    }
}

// ---------------- K3: merge window partials: gn, Sglob, Ssoft, Shard --------
// block = b; slots 8b..8b+7 hold the 8 n-window partials.
__global__ __launch_bounds__(256) void k_post(
    const float* __restrict__ U, const float* __restrict__ PG2,
    const float* __restrict__ PM2, const float* __restrict__ PS2,
    const float* __restrict__ PH2, const float* __restrict__ misc,
    float* __restrict__ Sglob, float* __restrict__ Ssoft,
    float* __restrict__ Shard) {
  int bI = blockIdx.x;
  int t = threadIdx.x;
  __shared__ float red[4];
  __shared__ float gnS;
  // gn[b] = max(||u||/N, eps), u[c] = sum of 8 window partials
  float sq = 0.f;
  #pragma unroll
  for (int half = 0; half < 2; half++) {
    int c = t + 256 * half;
    float u = 0.f;
    #pragma unroll
    for (int j = 0; j < 8; j++) u += U[((size_t)bI * 8 + j) * C + c];
    sq += u * u;
  }
  float wsum = wave_reduce_sum(sq);
  if ((t & 63) == 0) red[t >> 6] = wsum;
  __syncthreads();
  if (t == 0) {
    float s = red[0] + red[1] + red[2] + red[3];
    gnS = fmaxf(sqrtf(s) * (1.0f / (float)N), 1e-12f);
  }
  __syncthreads();
  float gn = gnS;
  int k = t;
  size_t p0 = (size_t)bI * 8 * 256 + k;
  float g = 0.f;
  #pragma unroll
  for (int j = 0; j < 8; j++) g += PG2[p0 + j * 256];
  Sglob[(size_t)bI * K + k] = misc[0] * g * (1.0f / (float)N) / gn;
  float M = -1e30f;
  #pragma unroll
  for (int j = 0; j < 8; j++) M = fmaxf(M, PM2[p0 + j * 256]);
  float S = 0.f;
  #pragma unroll
  for (int j = 0; j < 8; j++) S += PS2[p0 + j * 256] * __expf(PM2[p0 + j * 256] - M);
  Ssoft[(size_t)bI * K + k] = M + __logf(S);
  float H = -1e30f;
  #pragma unroll
  for (int j = 0; j < 8; j++) H = fmaxf(H, PH2[p0 + j * 256]);
  Shard[(size_t)bI * K + k] = H;
}

// ---------------- K4: focal CE per row/col of each 256x256 matrix -----------
__global__ __launch_bounds__(256) void k_focal(const float* __restrict__ Sglob,
                                               const float* __restrict__ Ssoft,
                                               const float* __restrict__ Shard,
                                               float* __restrict__ misc) {
  int job = blockIdx.y;   // 0..5: {glob,globT,soft,softT,hard,hardT}
  int i = blockIdx.x;
  int t = threadIdx.x;
  const float* M = job < 2 ? Sglob : (job < 4 ? Ssoft : Shard);
  float v = (job & 1) ? M[(size_t)t * K + i] : M[(size_t)i * K + t];
  __shared__ float red[4];
  float mx = wave_reduce_max(v);
  if ((t & 63) == 0) red[t >> 6] = mx;
  __syncthreads();
  mx = fmaxf(fmaxf(red[0], red[1]), fmaxf(red[2], red[3]));
  __syncthreads();
  float sv = wave_reduce_sum(v);
  if ((t & 63) == 0) red[t >> 6] = sv;
  __syncthreads();
  float sumv = red[0] + red[1] + red[2] + red[3];
  __syncthreads();
  float se = wave_reduce_sum(expf(v - mx));
  if ((t & 63) == 0) red[t >> 6] = se;
  __syncthreads();
  if (t == 0) {
    float sumexp = red[0] + red[1] + red[2] + red[3];
    float logZ = mx + logf(sumexp);
    float diag = M[(size_t)i * K + i];
    float nll = logZ - diag;
    float smooth = logZ - sumv * (1.0f / 256.0f);
    float ce = 0.75f * nll + 0.25f * smooth;
    float pt = expf(-ce);
    float fo = (1.0f - pt) * (1.0f - pt) * ce;
    atomicAdd(&misc[1 + job], fo);
  }
}

// ---------------- K5: combine ----------------
__global__ void k_finish(const float* __restrict__ misc, float* __restrict__ out) {
  float lg = misc[1] + misc[2];
  float ls = misc[3] + misc[4];
  float lh = misc[5] + misc[6];
  out[0] = (0.2f * lg + 0.3f * ls + 0.5f * lh) * 0.5f * (1.0f / 256.0f);
}

extern "C" void kernel_launch(void* const* d_in, const int* in_sizes, int n_in,
                              void* d_out, int out_size, void* d_ws, size_t ws_size,
                              hipStream_t stream) {
  const float* yolo = (const float*)d_in[0];   // (B, C, N)
  const float* clip = (const float*)d_in[1];   // (B, C)
  const float* ls   = (const float*)d_in[2];   // (1,)
  float* out = (float*)d_out;
  float* ws = (float*)d_ws;
  unsigned short* clipnb = (unsigned short*)(ws + OFF_CLIPNB);
  float* U     = ws + OFF_U;
  float* PM2   = ws + OFF_PM;
  float* PS2   = ws + OFF_PS;
  float* PH2   = ws + OFF_PH;
  float* PG2   = ws + OFF_PG;
  float* Sglob = ws + OFF_SGLOB;
  float* Ssoft = ws + OFF_SSOFT;
  float* Shard = ws + OFF_SHARD;
  float* misc  = ws + OFF_MISC;

  k_rownorm<<<256, 256, 0, stream>>>(clip, ls, clipnb, misc);
  k_main_mfma<<<NSLOT, 512, 0, stream>>>(yolo, clipnb, misc, U,
                                         PM2, PS2, PH2, PG2);
  k_post<<<256, 256, 0, stream>>>(U, PG2, PM2, PS2, PH2, misc,
                                  Sglob, Ssoft, Shard);
  k_focal<<<dim3(256, 6), 256, 0, stream>>>(Sglob, Ssoft, Shard, misc);
  k_finish<<<1, 1, 0, stream>>>(misc, out);
}